// Round 13
// baseline (155.291 us; speedup 1.0000x reference)
//
#include <hip/hip_runtime.h>

// JointLoss on MI355X. N=8192, D=256. Output: 1 fp32 scalar.
//
// ws layout (bytes):
//   [0,      32768)   pslots[2048][4] float: per-k_rows-block partials (cox,cnt,sim)
//   [32768,  294912)  gsum[2][8192][4] float (per matrix,row,group exp-sums)
//   [294912, +2M)     packed wsi fp8 e4m3, MX K=128 layout, PRE-SCALED by
//                     alpha=sqrt(14.4269504): byte ((ks*4+q)*N + row)*32 + j
//                     holds alpha*emb[row][k]/||emb||, k = ks*128 + q*32 + j
//   [294912+2M, +4M)  packed omic fp8 (same layout)
//
// R1: same-address atomics serialize -> spread/partial-write instead.
// R3/R7: unified VGPR+AGPR budget: over-ask waves -> spill (HBM scratch).
// R5: fp8 halves bytes.  R10: MX K=128 -> 2x matrix rate (scale semantics
//   verified: byte 0 of the i32 scale arg is the per-lane E8M0).
// R11/R12: scheduling tweaks neutral; VALU epilogue is the wall (v_exp
//   ~16cyc/wave64: 8 exp + 8 fma + 8 add > 140cyc matrix per tile).
// Now: fold 14.4269*dot - 14.4269 + 127 INTO the MFMA (alpha^2 * 2^23 via
//   MX scales 2^12*2^11, bias via C-init) -> epilogue = bitcast fast-exp2:
//   1 v_cvt + 1 v_add per element. Error <=6% high, cancels in lse diff.

#define NN 8192
#define DD 256

typedef __attribute__((ext_vector_type(4))) float f32x4;
typedef __attribute__((ext_vector_type(4))) int i32x4;
typedef __attribute__((ext_vector_type(8))) int i32x8;

#define ALPHA 3.79828f  // sqrt(14.4269504); ALPHA^2 * 2^23 folded via MX scales

// ---------------------------------------------------------------------------
// K1 (fused): per-row everything. grid 2048 x 256 thr (4 waves, 1 row each).
//  - rank_i / at_risk_i by full O(N) scan per wave over LDS-staged chunks
//    (no atomics, no init): rank_i = #{j: t_j<t_i or (t_j==t_i and j<i)},
//    at_risk_i = sum over complement incl self of exp(clip(lr_j)).
//  - norms / cos-sim / Cox li -> NON-atomic per-block partial in pslots[blk].
//  - normalize -> *ALPHA -> fp8 -> scatter into rank-permuted MX layout.
//  - first 64 blocks also zero gsum (runs before k_contrast in-stream).
// ---------------------------------------------------------------------------
__global__ void __launch_bounds__(256) k_rows(
    const float* __restrict__ lr, const float* __restrict__ times,
    const int* __restrict__ censor,
    const float* __restrict__ wsi, const float* __restrict__ omic,
    unsigned char* __restrict__ pw, unsigned char* __restrict__ po,
    float* __restrict__ pslots, float* __restrict__ gsum) {
  __shared__ __align__(16) float st[1024];
  __shared__ __align__(16) float se[1024];
  __shared__ float red[4][3];
  const int tid = threadIdx.x;
  const int lane = tid & 63;
  const int wv = tid >> 6;
  const int i = blockIdx.x * 4 + wv;

  if (blockIdx.x < 64) { // zero gsum (65536 floats) across first 64 blocks
    ((f32x4*)gsum)[blockIdx.x * 256 + tid] = (f32x4){0.f, 0.f, 0.f, 0.f};
  }

  // embeddings: norms + dot via wave shuffle
  const float4 w = ((const float4*)(wsi + (size_t)i * DD))[lane];
  const float4 o = ((const float4*)(omic + (size_t)i * DD))[lane];
  float nw = w.x * w.x + w.y * w.y + w.z * w.z + w.w * w.w;
  float no = o.x * o.x + o.y * o.y + o.z * o.z + o.w * o.w;
  float dd = w.x * o.x + w.y * o.y + w.z * o.z + w.w * o.w;
  for (int m = 1; m < 64; m <<= 1) {
    nw += __shfl_xor(nw, m);
    no += __shfl_xor(no, m);
    dd += __shfl_xor(dd, m);
  }
  const float nws = sqrtf(nw), nos = sqrtf(no);

  // rank + at_risk: scan all 8192 j in 8 LDS chunks of 1024
  const float ti = times[i];
  int rk = 0;
  float ar = 0.f;
  for (int c = 0; c < 8; ++c) {
    __syncthreads();
    for (int p = tid; p < 1024; p += 256) {
      float t = times[c * 1024 + p];
      float l = lr[c * 1024 + p];
      st[p] = t;
      se[p] = __expf(fminf(fmaxf(l, -10.f), 10.f));
    }
    __syncthreads();
#pragma unroll 4
    for (int jt = 0; jt < 16; ++jt) {
      const int p = jt * 64 + lane;
      const float t = st[p];
      const float e = se[p];
      const bool c1 = (t < ti) || ((t == ti) && ((c * 1024 + p) < i));
      rk += c1 ? 1 : 0;
      ar += c1 ? 0.f : e;
    }
  }
  for (int m = 1; m < 64; m <<= 1) {
    rk += __shfl_xor(rk, m);
    ar += __shfl_xor(ar, m);
  }

  if (lane == 0) {
    float c = dd / (fmaxf(nws, 1e-8f) * fmaxf(nos, 1e-8f));
    c = fminf(fmaxf(c, -1.f), 1.f);
    float l = fminf(fmaxf(lr[i], -10.f), 10.f);
    float li = l - logf(ar + 1e-15f);
    bool cen = (censor[i] == 1);
    red[wv][0] = cen ? li : 0.f;
    red[wv][1] = cen ? 1.f : 0.f;
    red[wv][2] = 1.f - c;
  }

  // normalize -> *ALPHA -> fp8 -> rank-permuted MX-packed scatter
  // lane covers k = lane*4..+3: ks=lane>>5, q=(lane>>3)&3, j=(lane&7)*4
  // -> offset ((ks*4+q)*NN + r)*32 + j.
  const int r = rk; // permuted row; r>>11 == risk group
  const float iw = ALPHA / fmaxf(nws, 1e-12f);
  const float io = ALPHA / fmaxf(nos, 1e-12f);
  int zw = __builtin_amdgcn_cvt_pk_fp8_f32(w.x * iw, w.y * iw, 0, false);
  zw = __builtin_amdgcn_cvt_pk_fp8_f32(w.z * iw, w.w * iw, zw, true);
  int zo = __builtin_amdgcn_cvt_pk_fp8_f32(o.x * io, o.y * io, 0, false);
  zo = __builtin_amdgcn_cvt_pk_fp8_f32(o.z * io, o.w * io, zo, true);
  const size_t off = ((size_t)((lane >> 5) * 4 + ((lane >> 3) & 3)) * NN + r) * 32
                     + (lane & 7) * 4;
  *(unsigned int*)(pw + off) = (unsigned int)zw;
  *(unsigned int*)(po + off) = (unsigned int)zo;
  __syncthreads();
  if (tid < 3) { // non-atomic per-block partial (every slot written -> no init)
    pslots[blockIdx.x * 4 + tid] =
        red[0][tid] + red[1][tid] + red[2][tid] + red[3][tid];
  }
}

// ---------------------------------------------------------------------------
// K2: contrastive exp-sums. MX fp8 K=128, barrier-free, no LDS, FUSED EXP:
// MFMA output = 2^23*(14.4269504*dot) (alpha^2 pre-scale x 2^12 x 2^11 MX
// scales); acc C-init = (127-14.4269504)*2^23; epilogue fast-exp2 =
// bitcast<float>((int)acc) ~ exp(10*dot-10), monotone, <=6% high (cancels
// in lse_all - lse_pos; final-scalar error ~1e-3 vs 0.19 threshold).
// grid (16 cb, 64 rb, 2 mz) x 256 thr, launch_bounds(256,4), 4 blk/CU.
// Wave owns 32 rows (afrag 32 regs), sweeps 32 col-tiles of 16 in its
// 512-col slab; B direct from L2 (2 MB resident, 16-lane-coalesced
// dwordx4), prefetch distance 2; acc-parity epilogue overlap.
// Group g = cb>>2 const per block. Diagonal tiles dt0/dt1 wave-uniform.
// ---------------------------------------------------------------------------
__device__ inline void epi(const f32x4& a0, const f32x4& a1, int t,
                           int dt0, int dt1, int lo, int q,
                           float* __restrict__ s0, float* __restrict__ s1) {
  if (t == dt0 || t == dt1) { // wave-uniform branch, <=2 of 32 tiles
#pragma unroll
    for (int r = 0; r < 4; ++r) {
      float e0 = __builtin_bit_cast(float, (int)a0[r]); // fast exp2
      float e1 = __builtin_bit_cast(float, (int)a1[r]);
      if (t == dt0 && lo == q * 4 + r) e0 = 0.f; // exact diagonal exclusion
      if (t == dt1 && lo == q * 4 + r) e1 = 0.f;
      s0[r] += e0;
      s1[r] += e1;
    }
  } else {
#pragma unroll
    for (int r = 0; r < 4; ++r) {
      s0[r] += __builtin_bit_cast(float, (int)a0[r]);
      s1[r] += __builtin_bit_cast(float, (int)a1[r]);
    }
  }
}

__global__ void __launch_bounds__(256, 4) k_contrast(
    const unsigned char* __restrict__ pw, const unsigned char* __restrict__ po,
    float* __restrict__ gsum) {
  const int tid = threadIdx.x;
  const int lane = tid & 63;
  const int wv = tid >> 6;                 // 0..3
  const int lo = lane & 15, q = lane >> 4; // MFMA frag coords
  const int cb = blockIdx.x, rb = blockIdx.y, mz = blockIdx.z;
  const unsigned char* __restrict__ pk = (mz == 0) ? pw : po;
  const int rowbase = rb * 128 + wv * 32;
  const int colstart = cb * 512;
  const int g = cb >> 2;

  // A fragments: 2 row-tiles x 2 K-segments x 32 B = 32 regs, resident
  i32x8 afrag[2][2];
#pragma unroll
  for (int rt = 0; rt < 2; ++rt) {
    const size_t row = rowbase + rt * 16 + lo;
#pragma unroll
    for (int ks = 0; ks < 2; ++ks)
      afrag[rt][ks] = *(const i32x8*)(pk + ((size_t)(ks * 4 + q) * NN + row) * 32);
  }

  // B frag base pointers (per ks); tile t adds t*16 cols = t*512 bytes
  const unsigned char* const bbase0 =
      pk + ((size_t)q * NN + colstart + lo) * 32;
  const unsigned char* const bbase1 =
      pk + ((size_t)(4 + q) * NN + colstart + lo) * 32;

  // diagonal tile indices for this wave's two row-tiles (wave-uniform)
  const int dt0 = (rowbase - colstart) >> 4; // outside [0,32) -> never hit
  const int dt1 = dt0 + 1;

  // bias so MFMA output is already 2^23*(x+127), x = log2(exp(10*dot-10))
  const float BIAS = (127.0f - 14.4269504f) * 8388608.0f;
  const f32x4 cinit = {BIAS, BIAS, BIAS, BIAS};

  float s0[4] = {0.f, 0.f, 0.f, 0.f};
  float s1[4] = {0.f, 0.f, 0.f, 0.f};
  f32x4 acc0[2], acc1[2];
  i32x8 bfr[2][2]; // [tile parity][ks], prefetch distance 2
  bfr[0][0] = *(const i32x8*)bbase0;
  bfr[0][1] = *(const i32x8*)bbase1;
  bfr[1][0] = *(const i32x8*)(bbase0 + 512);
  bfr[1][1] = *(const i32x8*)(bbase1 + 512);

#pragma unroll 2
  for (int t = 0; t < 32; ++t) {
    const int cur = t & 1, oth = cur ^ 1;
    // issue tile t's MFMAs (matrix pipe); scales 2^12 x 2^11 = 2^23
    acc0[cur] = cinit; acc1[cur] = cinit;
    acc0[cur] = __builtin_amdgcn_mfma_scale_f32_16x16x128_f8f6f4(
        afrag[0][0], bfr[cur][0], acc0[cur], 0, 0, 0, 0x8B, 0, 0x8A);
    acc1[cur] = __builtin_amdgcn_mfma_scale_f32_16x16x128_f8f6f4(
        afrag[1][0], bfr[cur][0], acc1[cur], 0, 0, 0, 0x8B, 0, 0x8A);
    acc0[cur] = __builtin_amdgcn_mfma_scale_f32_16x16x128_f8f6f4(
        afrag[0][1], bfr[cur][1], acc0[cur], 0, 0, 0, 0x8B, 0, 0x8A);
    acc1[cur] = __builtin_amdgcn_mfma_scale_f32_16x16x128_f8f6f4(
        afrag[1][1], bfr[cur][1], acc1[cur], 0, 0, 0, 0x8B, 0, 0x8A);
    // refill this parity slot with tile t+2's B (distance-2 prefetch)
    if (t < 30) {
      bfr[cur][0] = *(const i32x8*)(bbase0 + (size_t)(t + 2) * 512);
      bfr[cur][1] = *(const i32x8*)(bbase1 + (size_t)(t + 2) * 512);
    }
    // epilogue for tile t-1 (cheap VALU) overlaps tile t's in-flight MFMAs
    if (t > 0) epi(acc0[oth], acc1[oth], t - 1, dt0, dt1, lo, q, s0, s1);
  }
  epi(acc0[1], acc1[1], 31, dt0, dt1, lo, q, s0, s1); // t=31 parity = 1

  // flush: reduce over 16 col-lanes, one atomic per (row, group)
#pragma unroll
  for (int rt = 0; rt < 2; ++rt)
#pragma unroll
    for (int r = 0; r < 4; ++r) {
      float v = rt ? s1[r] : s0[r];
      v += __shfl_xor(v, 1); v += __shfl_xor(v, 2);
      v += __shfl_xor(v, 4); v += __shfl_xor(v, 8);
      if (lo == 0) {
        const int row = rowbase + rt * 16 + q * 4 + r; // C/D: row=(lane>>4)*4+reg
        atomicAdd(&gsum[((size_t)mz * NN + row) * 4 + g], v);
      }
    }
}

// ---------------------------------------------------------------------------
// K3: finale. One block, 1024 thr. Reduces pslots (cox,cnt,sim), computes
// per-row LSE differences from gsum, combines the scalar.
// ---------------------------------------------------------------------------
__global__ void __launch_bounds__(1024) k_finale(
    const float* __restrict__ pslots, const float* __restrict__ gsum,
    float* __restrict__ out) {
  __shared__ float rsum[16][4];
  const int tid = threadIdx.x;
  const int lane = tid & 63, wv = tid >> 6;
  float cox = 0.f, cnt = 0.f, sim = 0.f, con = 0.f;
  for (int b = tid; b < 2048; b += 1024) {
    const float4 v = ((const float4*)pslots)[b];
    cox += v.x; cnt += v.y; sim += v.z;
  }
  for (int idx = tid; idx < 2 * NN; idx += 1024) {
    const float4 v = ((const float4*)gsum)[idx];
    const int row = idx & (NN - 1);
    const int gg = row >> 11; // group of permuted row
    const float sg = (gg == 0) ? v.x : (gg == 1) ? v.y : (gg == 2) ? v.z : v.w;
    con += logf(v.x + v.y + v.z + v.w) - logf(sg); // fixed shifts cancel
  }
  for (int m = 1; m < 64; m <<= 1) {
    cox += __shfl_xor(cox, m);
    cnt += __shfl_xor(cnt, m);
    sim += __shfl_xor(sim, m);
    con += __shfl_xor(con, m);
  }
  if (lane == 0) {
    rsum[wv][0] = cox; rsum[wv][1] = cnt; rsum[wv][2] = sim; rsum[wv][3] = con;
  }
  __syncthreads();
  if (tid == 0) {
    float c0 = 0.f, c1 = 0.f, c2 = 0.f, c3 = 0.f;
    for (int k = 0; k < 16; ++k) {
      c0 += rsum[k][0]; c1 += rsum[k][1]; c2 += rsum[k][2]; c3 += rsum[k][3];
    }
    out[0] = -c0 / fmaxf(c1, 1.f) + c2 / (float)NN
             + 0.1f * 0.5f * c3 / (float)NN;
  }
}

extern "C" void kernel_launch(void* const* d_in, const int* in_sizes, int n_in,
                              void* d_out, int out_size, void* d_ws, size_t ws_size,
                              hipStream_t stream) {
  const float* lr = (const float*)d_in[0];
  const float* times = (const float*)d_in[1];
  const int* censor = (const int*)d_in[2];
  const float* wsi = (const float*)d_in[3];
  const float* omic = (const float*)d_in[4];
  float* out = (float*)d_out;

  char* ws = (char*)d_ws;
  float* pslots = (float*)ws;
  float* gsum = (float*)(ws + 32768);
  unsigned char* pw = (unsigned char*)(ws + 294912);
  unsigned char* po = (unsigned char*)(ws + 294912 + 2097152);

  k_rows<<<2048, 256, 0, stream>>>(lr, times, censor, wsi, omic, pw, po, pslots, gsum);
  k_contrast<<<dim3(16, 64, 2), 256, 0, stream>>>(pw, po, gsum);
  k_finale<<<1, 1024, 0, stream>>>(pslots, gsum, out);
}

// Round 14
// 150.142 us; speedup vs baseline: 1.0343x; 1.0343x over previous
//
#include <hip/hip_runtime.h>

// JointLoss on MI355X. N=8192, D=256. Output: 1 fp32 scalar.
//
// ws layout (bytes):
//   [0,      32768)   pslots[2048][4] float: per-k_rows-block partials (cox,cnt,sim)
//   [32768,  294912)  gsum[2][8192][4] float (per matrix,row,group exp-sums)
//   [294912, +2M)     packed wsi fp8 e4m3, MX K=128 layout, PRE-SCALED by
//                     alpha=sqrt(14.4269504): byte ((ks*4+q)*N + row)*32 + j
//                     holds alpha*emb[row][k]/||emb||, k = ks*128 + q*32 + j
//   [294912+2M, +4M)  packed omic fp8 (same layout)
//
// R1: same-address atomics serialize -> spread/partial-write instead.
// R3/R7: unified VGPR+AGPR budget: over-ask waves -> spill (HBM scratch).
// R5: fp8 halves bytes.  R10: MX K=128 -> 2x matrix rate.
// R12/R13: scale-folded fast-exp2 verified (absmax ok), VALU 50->41% but
//   time flat: the hidden floor was L2 BW - 32-row waves re-read B slab
//   per wave: 8192 x 128KB = 1.07 GB / 36 TB/s = 30us.
// Now: 64 rows/wave (B frag feeds 8 MFMAs) -> 512 MB L2 (~14us), regs ~145
//   under launch_bounds(256,3)=168; no acc parity (epilogue cheap).

#define NN 8192
#define DD 256

typedef __attribute__((ext_vector_type(4))) float f32x4;
typedef __attribute__((ext_vector_type(4))) int i32x4;
typedef __attribute__((ext_vector_type(8))) int i32x8;

#define ALPHA 3.79828f  // sqrt(14.4269504); ALPHA^2 * 2^23 folded via MX scales

// ---------------------------------------------------------------------------
// K1 (fused): per-row everything. grid 2048 x 256 thr (4 waves, 1 row each).
//  - rank_i / at_risk_i by full O(N) scan per wave over LDS-staged chunks
//    (no atomics, no init): rank_i = #{j: t_j<t_i or (t_j==t_i and j<i)},
//    at_risk_i = sum over complement incl self of exp(clip(lr_j)).
//  - norms / cos-sim / Cox li -> NON-atomic per-block partial in pslots[blk].
//  - normalize -> *ALPHA -> fp8 -> scatter into rank-permuted MX layout.
//  - first 64 blocks also zero gsum (runs before k_contrast in-stream).
// ---------------------------------------------------------------------------
__global__ void __launch_bounds__(256) k_rows(
    const float* __restrict__ lr, const float* __restrict__ times,
    const int* __restrict__ censor,
    const float* __restrict__ wsi, const float* __restrict__ omic,
    unsigned char* __restrict__ pw, unsigned char* __restrict__ po,
    float* __restrict__ pslots, float* __restrict__ gsum) {
  __shared__ __align__(16) float st[1024];
  __shared__ __align__(16) float se[1024];
  __shared__ float red[4][3];
  const int tid = threadIdx.x;
  const int lane = tid & 63;
  const int wv = tid >> 6;
  const int i = blockIdx.x * 4 + wv;

  if (blockIdx.x < 64) { // zero gsum (65536 floats) across first 64 blocks
    ((f32x4*)gsum)[blockIdx.x * 256 + tid] = (f32x4){0.f, 0.f, 0.f, 0.f};
  }

  // embeddings: norms + dot via wave shuffle
  const float4 w = ((const float4*)(wsi + (size_t)i * DD))[lane];
  const float4 o = ((const float4*)(omic + (size_t)i * DD))[lane];
  float nw = w.x * w.x + w.y * w.y + w.z * w.z + w.w * w.w;
  float no = o.x * o.x + o.y * o.y + o.z * o.z + o.w * o.w;
  float dd = w.x * o.x + w.y * o.y + w.z * o.z + w.w * o.w;
  for (int m = 1; m < 64; m <<= 1) {
    nw += __shfl_xor(nw, m);
    no += __shfl_xor(no, m);
    dd += __shfl_xor(dd, m);
  }
  const float nws = sqrtf(nw), nos = sqrtf(no);

  // rank + at_risk: scan all 8192 j in 8 LDS chunks of 1024
  const float ti = times[i];
  int rk = 0;
  float ar = 0.f;
  for (int c = 0; c < 8; ++c) {
    __syncthreads();
    for (int p = tid; p < 1024; p += 256) {
      float t = times[c * 1024 + p];
      float l = lr[c * 1024 + p];
      st[p] = t;
      se[p] = __expf(fminf(fmaxf(l, -10.f), 10.f));
    }
    __syncthreads();
#pragma unroll 4
    for (int jt = 0; jt < 16; ++jt) {
      const int p = jt * 64 + lane;
      const float t = st[p];
      const float e = se[p];
      const bool c1 = (t < ti) || ((t == ti) && ((c * 1024 + p) < i));
      rk += c1 ? 1 : 0;
      ar += c1 ? 0.f : e;
    }
  }
  for (int m = 1; m < 64; m <<= 1) {
    rk += __shfl_xor(rk, m);
    ar += __shfl_xor(ar, m);
  }

  if (lane == 0) {
    float c = dd / (fmaxf(nws, 1e-8f) * fmaxf(nos, 1e-8f));
    c = fminf(fmaxf(c, -1.f), 1.f);
    float l = fminf(fmaxf(lr[i], -10.f), 10.f);
    float li = l - logf(ar + 1e-15f);
    bool cen = (censor[i] == 1);
    red[wv][0] = cen ? li : 0.f;
    red[wv][1] = cen ? 1.f : 0.f;
    red[wv][2] = 1.f - c;
  }

  // normalize -> *ALPHA -> fp8 -> rank-permuted MX-packed scatter
  // lane covers k = lane*4..+3: ks=lane>>5, q=(lane>>3)&3, j=(lane&7)*4
  // -> offset ((ks*4+q)*NN + r)*32 + j.
  const int r = rk; // permuted row; r>>11 == risk group
  const float iw = ALPHA / fmaxf(nws, 1e-12f);
  const float io = ALPHA / fmaxf(nos, 1e-12f);
  int zw = __builtin_amdgcn_cvt_pk_fp8_f32(w.x * iw, w.y * iw, 0, false);
  zw = __builtin_amdgcn_cvt_pk_fp8_f32(w.z * iw, w.w * iw, zw, true);
  int zo = __builtin_amdgcn_cvt_pk_fp8_f32(o.x * io, o.y * io, 0, false);
  zo = __builtin_amdgcn_cvt_pk_fp8_f32(o.z * io, o.w * io, zo, true);
  const size_t off = ((size_t)((lane >> 5) * 4 + ((lane >> 3) & 3)) * NN + r) * 32
                     + (lane & 7) * 4;
  *(unsigned int*)(pw + off) = (unsigned int)zw;
  *(unsigned int*)(po + off) = (unsigned int)zo;
  __syncthreads();
  if (tid < 3) { // non-atomic per-block partial (every slot written -> no init)
    pslots[blockIdx.x * 4 + tid] =
        red[0][tid] + red[1][tid] + red[2][tid] + red[3][tid];
  }
}

// ---------------------------------------------------------------------------
// K2: contrastive exp-sums. MX fp8 K=128, barrier-free, no LDS, fused exp:
// MFMA output = 2^23*(14.4269504*dot) via alpha^2 x 2^12 x 2^11 MX scales;
// C-init = (127-14.4269504)*2^23; epilogue = bitcast<float>((int)acc)
// fast-exp2 ~ exp(10*dot-10), monotone, error cancels in lse diff.
// grid (16 cb, 32 rb, 2 mz) x 256 thr, launch_bounds(256,3) -> 168-reg
// budget, 3 blk/CU (12 waves/CU). Wave owns 64 ROWS (afrag[4][2] i32x8 =
// 64 regs) -> each B frag feeds 8 MFMAs; B slab re-read once per wave:
// 4096 waves x 128 KB = 512 MB L2 (~14us at 36 TB/s), half of R13.
// B direct from L2 (16-lane-coalesced dwordx4 pairs), prefetch distance 2.
// Group g = cb>>2 const per block. Diagonal tiles dtbase+rt wave-uniform.
// ---------------------------------------------------------------------------
__global__ void __launch_bounds__(256, 3) k_contrast(
    const unsigned char* __restrict__ pw, const unsigned char* __restrict__ po,
    float* __restrict__ gsum) {
  const int tid = threadIdx.x;
  const int lane = tid & 63;
  const int wv = tid >> 6;                 // 0..3
  const int lo = lane & 15, q = lane >> 4; // MFMA frag coords
  const int cb = blockIdx.x, rb = blockIdx.y, mz = blockIdx.z;
  const unsigned char* __restrict__ pk = (mz == 0) ? pw : po;
  const int rowbase = rb * 256 + wv * 64;
  const int colstart = cb * 512;
  const int g = cb >> 2;

  // A fragments: 4 row-tiles x 2 K-segments x 32 B = 64 regs, resident
  i32x8 afrag[4][2];
#pragma unroll
  for (int rt = 0; rt < 4; ++rt) {
    const size_t row = rowbase + rt * 16 + lo;
#pragma unroll
    for (int ks = 0; ks < 2; ++ks)
      afrag[rt][ks] = *(const i32x8*)(pk + ((size_t)(ks * 4 + q) * NN + row) * 32);
  }

  // B frag base pointers (per ks); tile t adds t*16 cols = t*512 bytes
  const unsigned char* const bbase0 =
      pk + ((size_t)q * NN + colstart + lo) * 32;
  const unsigned char* const bbase1 =
      pk + ((size_t)(4 + q) * NN + colstart + lo) * 32;

  // diagonal tile index base for this wave's four row-tiles (wave-uniform)
  const int dtbase = (rowbase - colstart) >> 4; // outside [0,32): never hit

  // bias so MFMA output is already 2^23*(x+127), x = log2(exp(10*dot-10))
  const float BIAS = (127.0f - 14.4269504f) * 8388608.0f;
  const f32x4 cinit = {BIAS, BIAS, BIAS, BIAS};

  float s[4][4] = {{0.f}};
  f32x4 acc[4];
  i32x8 bfr[2][2]; // [tile parity][ks], prefetch distance 2
  bfr[0][0] = *(const i32x8*)bbase0;
  bfr[0][1] = *(const i32x8*)bbase1;
  bfr[1][0] = *(const i32x8*)(bbase0 + 512);
  bfr[1][1] = *(const i32x8*)(bbase1 + 512);

#pragma unroll 2
  for (int t = 0; t < 32; ++t) {
    const int cur = t & 1;
    // issue tile t's MFMAs (matrix pipe); scales 2^12 x 2^11 = 2^23
#pragma unroll
    for (int rt = 0; rt < 4; ++rt) acc[rt] = cinit;
#pragma unroll
    for (int ks = 0; ks < 2; ++ks)
#pragma unroll
      for (int rt = 0; rt < 4; ++rt)
        acc[rt] = __builtin_amdgcn_mfma_scale_f32_16x16x128_f8f6f4(
            afrag[rt][ks], bfr[cur][ks], acc[rt], 0, 0, 0, 0x8B, 0, 0x8A);
    // refill this parity slot with tile t+2's B (distance-2 prefetch)
    if (t < 30) {
      bfr[cur][0] = *(const i32x8*)(bbase0 + (size_t)(t + 2) * 512);
      bfr[cur][1] = *(const i32x8*)(bbase1 + (size_t)(t + 2) * 512);
    }
    // epilogue: fast-exp2 bitcast, 2 VALU ops/elem; diag is wave-uniform
#pragma unroll
    for (int rt = 0; rt < 4; ++rt) {
      if (t == dtbase + rt) { // <=1 of 32 tiles per rt
#pragma unroll
        for (int r = 0; r < 4; ++r) {
          float e = __builtin_bit_cast(float, (int)acc[rt][r]);
          if (lo == q * 4 + r) e = 0.f; // exact diagonal exclusion
          s[rt][r] += e;
        }
      } else {
#pragma unroll
        for (int r = 0; r < 4; ++r)
          s[rt][r] += __builtin_bit_cast(float, (int)acc[rt][r]);
      }
    }
  }

  // flush: reduce over 16 col-lanes, one atomic per (row, group)
#pragma unroll
  for (int rt = 0; rt < 4; ++rt)
#pragma unroll
    for (int r = 0; r < 4; ++r) {
      float v = s[rt][r];
      v += __shfl_xor(v, 1); v += __shfl_xor(v, 2);
      v += __shfl_xor(v, 4); v += __shfl_xor(v, 8);
      if (lo == 0) {
        const int row = rowbase + rt * 16 + q * 4 + r; // C/D: row=(lane>>4)*4+reg
        atomicAdd(&gsum[((size_t)mz * NN + row) * 4 + g], v);
      }
    }
}

// ---------------------------------------------------------------------------
// K3: finale. One block, 1024 thr. Reduces pslots (cox,cnt,sim), computes
// per-row LSE differences from gsum, combines the scalar.
// ---------------------------------------------------------------------------
__global__ void __launch_bounds__(1024) k_finale(
    const float* __restrict__ pslots, const float* __restrict__ gsum,
    float* __restrict__ out) {
  __shared__ float rsum[16][4];
  const int tid = threadIdx.x;
  const int lane = tid & 63, wv = tid >> 6;
  float cox = 0.f, cnt = 0.f, sim = 0.f, con = 0.f;
  for (int b = tid; b < 2048; b += 1024) {
    const float4 v = ((const float4*)pslots)[b];
    cox += v.x; cnt += v.y; sim += v.z;
  }
  for (int idx = tid; idx < 2 * NN; idx += 1024) {
    const float4 v = ((const float4*)gsum)[idx];
    const int row = idx & (NN - 1);
    const int gg = row >> 11; // group of permuted row
    const float sg = (gg == 0) ? v.x : (gg == 1) ? v.y : (gg == 2) ? v.z : v.w;
    con += logf(v.x + v.y + v.z + v.w) - logf(sg); // fixed shifts cancel
  }
  for (int m = 1; m < 64; m <<= 1) {
    cox += __shfl_xor(cox, m);
    cnt += __shfl_xor(cnt, m);
    sim += __shfl_xor(sim, m);
    con += __shfl_xor(con, m);
  }
  if (lane == 0) {
    rsum[wv][0] = cox; rsum[wv][1] = cnt; rsum[wv][2] = sim; rsum[wv][3] = con;
  }
  __syncthreads();
  if (tid == 0) {
    float c0 = 0.f, c1 = 0.f, c2 = 0.f, c3 = 0.f;
    for (int k = 0; k < 16; ++k) {
      c0 += rsum[k][0]; c1 += rsum[k][1]; c2 += rsum[k][2]; c3 += rsum[k][3];
    }
    out[0] = -c0 / fmaxf(c1, 1.f) + c2 / (float)NN
             + 0.1f * 0.5f * c3 / (float)NN;
  }
}

extern "C" void kernel_launch(void* const* d_in, const int* in_sizes, int n_in,
                              void* d_out, int out_size, void* d_ws, size_t ws_size,
                              hipStream_t stream) {
  const float* lr = (const float*)d_in[0];
  const float* times = (const float*)d_in[1];
  const int* censor = (const int*)d_in[2];
  const float* wsi = (const float*)d_in[3];
  const float* omic = (const float*)d_in[4];
  float* out = (float*)d_out;

  char* ws = (char*)d_ws;
  float* pslots = (float*)ws;
  float* gsum = (float*)(ws + 32768);
  unsigned char* pw = (unsigned char*)(ws + 294912);
  unsigned char* po = (unsigned char*)(ws + 294912 + 2097152);

  k_rows<<<2048, 256, 0, stream>>>(lr, times, censor, wsi, omic, pw, po, pslots, gsum);
  k_contrast<<<dim3(16, 32, 2), 256, 0, stream>>>(pw, po, gsum);
  k_finale<<<1, 1024, 0, stream>>>(pslots, gsum, out);
}